// Round 7
// baseline (256.916 us; speedup 1.0000x reference)
//
#include <hip/hip_runtime.h>

// RNN: B=2048 chains, T=1024 steps, H=64, I=1.
// Round-7: latency-bound on the serial recurrence (r6: VALUBusy 74%, 26%
// stall, only 2 waves/SIMD of TLP). Fix: TWO independent chains per wave
// (1024 blocks = 1 wave/SIMD) -> chain A's LDS round-trip/tanh latency
// hides under chain B's FMA chain and vice versa. W/bias registers shared
// by both chains. Plus: pk_mul first-column accumulator init (-14 movs/step,
// bitwise-identical math). Rotated-row W + 3-op DPP ring reduce-scatter,
// one tanh per lane per chain. Single wave/block -> DS in-order, no barriers.

constexpr int T_STEPS = 1024;
constexpr int H = 64;

typedef float v2f __attribute__((ext_vector_type(2)));
typedef float v4f __attribute__((ext_vector_type(4)));

__device__ __forceinline__ float dpp_rotfwd_add(float t, float a) {
    // within each quad: lane q receives t from lane (q+1)&3, then adds a.
    int y = __builtin_amdgcn_mov_dpp(__builtin_bit_cast(int, t), 0x39, 0xF, 0xF, true);
    return __builtin_bit_cast(float, y) + a;
}

__device__ __forceinline__ float tanh_fast(float s) {
    // tanh(s) = 1 - 2/(exp2(s*2log2e)+1); saturates correctly at +-1.
    const float e = __builtin_amdgcn_exp2f(s * 2.88539008177792681472f);
    return 1.f - 2.f * __builtin_amdgcn_rcpf(e + 1.f);
}

__device__ __forceinline__ v2f vlo(v4f v) { return __builtin_shufflevector(v, v, 0, 1); }
__device__ __forceinline__ v2f vhi(v4f v) { return __builtin_shufflevector(v, v, 2, 3); }

__global__
__attribute__((amdgpu_flat_work_group_size(64, 64), amdgpu_waves_per_eu(1, 1)))
void rnn_fused(
    const float* __restrict__ x,      // [B, T, 1]
    const float* __restrict__ W_ih,   // [H, 1]
    const float* __restrict__ W_hh,   // [H, H] row-major
    const float* __restrict__ b_ih,   // [H]
    const float* __restrict__ b_hh,   // [H]
    const float* __restrict__ W_out,  // [1, H]
    const float* __restrict__ b_out,  // [1]
    float* __restrict__ out)          // [B, 1]
{
    const int bid  = blockIdx.x;      // handles chains 2*bid and 2*bid+1
    const int lane = threadIdx.x;     // 0..63
    const int og   = lane >> 2;
    const int kg   = lane & 3;        // k-slice [16kg, 16kg+16)

    __shared__ v4f xsA[T_STEPS / 4];  // 4 KiB: x[2bid, :]
    __shared__ v4f xsB[T_STEPS / 4];  // 4 KiB: x[2bid+1, :]
    __shared__ v4f hA0[H / 4], hA1[H / 4];   // chain A ping/pong
    __shared__ v4f hB0[H / 4], hB1[H / 4];   // chain B ping/pong

    // Stage x rows for both chains, coalesced float4.
    const v4f* xrowA = reinterpret_cast<const v4f*>(x + (size_t)(2 * bid)     * T_STEPS);
    const v4f* xrowB = reinterpret_cast<const v4f*>(x + (size_t)(2 * bid + 1) * T_STEPS);
    #pragma unroll
    for (int k = 0; k < T_STEPS / 4 / 64; ++k) {
        xsA[lane + 64 * k] = xrowA[lane + 64 * k];
        xsB[lane + 64 * k] = xrowB[lane + 64 * k];
    }

    // W tile as float2 pairs, rotated rows: slot r holds row 4og+((kg+r)&3),
    // cols [16kg,16kg+16). SHARED between the two chains.
    v2f w2[4][8];
    #pragma unroll
    for (int r = 0; r < 4; ++r) {
        const int row = 4 * og + ((kg + r) & 3);
        const float* src = W_hh + (size_t)row * H + 16 * kg;
        #pragma unroll
        for (int c2 = 0; c2 < 8; ++c2)
            w2[r][c2] = *reinterpret_cast<const v2f*>(src + 2 * c2);
    }
    #pragma unroll
    for (int r = 0; r < 4; ++r)
        #pragma unroll
        for (int c2 = 0; c2 < 8; ++c2)
            asm volatile("" : "+v"(w2[r][c2]));   // keep in arch VGPRs

    // Per-lane scalars for OUR output (index = lane); shared by both chains.
    const float wih  = W_ih[lane];
    const float bias = b_ih[lane] + b_hh[lane];
    const float wout = W_out[lane];

    reinterpret_cast<float*>(hA0)[lane] = 0.f;   // h0 = 0 (both chains)
    reinterpret_cast<float*>(hB0)[lane] = 0.f;

    // One recurrence step for one chain. Returns tanh output h_new[lane].
    auto step = [&](float xv, const v4f* __restrict__ hr,
                    float* __restrict__ hw) -> float {
        const v4f* h4 = hr + 4 * kg;
        const v4f hv0 = h4[0], hv1 = h4[1], hv2 = h4[2], hv3 = h4[3];
        const float seed = fmaf(xv, wih, bias);
        // c=0 initializes accumulators (pk_mul; accL[0] seeded) -- bitwise
        // identical to fma-into-zero, minus 14 v_movs.
        v2f accL[4], accM[4];
        accL[0] = __builtin_elementwise_fma(vlo(hv0), w2[0][0], v2f{seed, 0.f});
        accL[1] = vlo(hv0) * w2[1][0];
        accL[2] = vlo(hv0) * w2[2][0];
        accL[3] = vlo(hv0) * w2[3][0];
        accM[0] = vhi(hv0) * w2[0][1];
        accM[1] = vhi(hv0) * w2[1][1];
        accM[2] = vhi(hv0) * w2[2][1];
        accM[3] = vhi(hv0) * w2[3][1];
        #pragma unroll
        for (int r = 0; r < 4; ++r) {
            accL[r] = __builtin_elementwise_fma(vlo(hv1), w2[r][2], accL[r]);
            accM[r] = __builtin_elementwise_fma(vhi(hv1), w2[r][3], accM[r]);
        }
        #pragma unroll
        for (int r = 0; r < 4; ++r) {
            accL[r] = __builtin_elementwise_fma(vlo(hv2), w2[r][4], accL[r]);
            accM[r] = __builtin_elementwise_fma(vhi(hv2), w2[r][5], accM[r]);
        }
        #pragma unroll
        for (int r = 0; r < 4; ++r) {
            accL[r] = __builtin_elementwise_fma(vlo(hv3), w2[r][6], accL[r]);
            accM[r] = __builtin_elementwise_fma(vhi(hv3), w2[r][7], accM[r]);
        }
        float a[4];
        #pragma unroll
        for (int r = 0; r < 4; ++r) {
            const v2f s2 = accL[r] + accM[r];
            a[r] = s2.x + s2.y;
        }
        // Reduce-scatter ring: lane q ends with output 4og+q's full sum.
        float t = a[1];
        t = dpp_rotfwd_add(t, a[2]);
        t = dpp_rotfwd_add(t, a[3]);
        t = dpp_rotfwd_add(t, a[0]);
        const float hn = tanh_fast(t);
        hw[lane] = hn;                      // stride-4 ds_write_b32: free
        return hn;
    };

    float hnA = 0.f, hnB = 0.f;
    #pragma unroll 1
    for (int t4 = 0; t4 < T_STEPS / 4; ++t4) {
        const v4f xqA = xsA[t4];            // uniform ds_read_b128
        const v4f xqB = xsB[t4];
        // A and B steps are independent: B's compute hides A's LDS
        // round-trip + tanh latency, and vice versa.
        hnA = step(xqA.x, hA0, reinterpret_cast<float*>(hA1));
        hnB = step(xqB.x, hB0, reinterpret_cast<float*>(hB1));
        hnA = step(xqA.y, hA1, reinterpret_cast<float*>(hA0));
        hnB = step(xqB.y, hB1, reinterpret_cast<float*>(hB0));
        hnA = step(xqA.z, hA0, reinterpret_cast<float*>(hA1));
        hnB = step(xqB.z, hB0, reinterpret_cast<float*>(hB1));
        hnA = step(xqA.w, hA1, reinterpret_cast<float*>(hA0));
        hnB = step(xqB.w, hB1, reinterpret_cast<float*>(hB0));
    }

    // out = sigmoid(h . W_out + b_out) for both chains; h[i] lives in lane i.
    float pA = hnA * wout;
    float pB = hnB * wout;
    #pragma unroll
    for (int off = 1; off <= 32; off <<= 1) {
        pA += __shfl_xor(pA, off);
        pB += __shfl_xor(pB, off);
    }
    if (lane == 0) {
        const float bo = b_out[0];
        out[2 * bid]     = 1.f / (1.f + __expf(-(pA + bo)));
        out[2 * bid + 1] = 1.f / (1.f + __expf(-(pB + bo)));
    }
}

extern "C" void kernel_launch(void* const* d_in, const int* in_sizes, int n_in,
                              void* d_out, int out_size, void* d_ws, size_t ws_size,
                              hipStream_t stream)
{
    const float* x     = (const float*)d_in[0];
    const float* W_ih  = (const float*)d_in[1];
    const float* W_hh  = (const float*)d_in[2];
    const float* b_ih  = (const float*)d_in[3];
    const float* b_hh  = (const float*)d_in[4];
    const float* W_out = (const float*)d_in[5];
    const float* b_out = (const float*)d_in[6];
    float* out = (float*)d_out;

    const int B = out_size;          // 2048 chains, 2 per wave
    rnn_fused<<<B / 2, 64, 0, stream>>>(x, W_ih, W_hh, b_ih, b_hh, W_out, b_out, out);
}